// Round 6
// baseline (239.821 us; speedup 1.0000x reference)
//
#include <hip/hip_runtime.h>

typedef unsigned short u16;
typedef unsigned int   u32;
typedef __attribute__((ext_vector_type(8))) short bf8_t;   // 8 x bf16 (4 VGPRs)
typedef __attribute__((ext_vector_type(4))) float f4_t;    // 4 x fp32 acc

#define NB 256
#define NS 1024

__device__ __forceinline__ u16 f2bf(float f){   // RNE (used in prep only)
    u32 u = __float_as_uint(f);
    return (u16)((u + 0x7fffu + ((u >> 16) & 1u)) >> 16);
}
// 2 x fp32 -> packed bf16 (truncate), single v_perm_b32
__device__ __forceinline__ u32 pack_trunc(float lo, float hi){
    return __builtin_amdgcn_perm(__float_as_uint(hi), __float_as_uint(lo), 0x07060302u);
}

// ---- fused prep: blocks 0..511 -> per-(b,br) WeffT fragments + Cs (+y_trans);
//                  blocks 512..519 -> W (x-transform) B-fragment layout ----
__global__ __launch_bounds__(256) void prep_kernel(
    const float* __restrict__ y,    const float* __restrict__ wty,
    const float* __restrict__ bty,  const float* __restrict__ aty,
    const float* __restrict__ uid,  const float* __restrict__ ose, const float* __restrict__ zipc,
    const float* __restrict__ wlx,  const float* __restrict__ wnx,
    const float* __restrict__ lw1,  const float* __restrict__ lb1,
    const float* __restrict__ nw1,  const float* __restrict__ nb1,
    u32* __restrict__ wtf, u32* __restrict__ weff, float* __restrict__ cs)
{
    const int tid = threadIdx.x;
    const int bx  = blockIdx.x;

    if (bx >= 512) {
        // ---- wtf part: unit u = (br*16 + n*2 + ks)*64 + lane ----
        int u = (bx - 512)*256 + tid;   // 0..2047
        int lane = u & 63, fr = u >> 6;
        int br = fr >> 4, t = fr & 15, n = t >> 1, ks = t & 1;
        int q = lane >> 4, lm = lane & 15;
        const float* W = br ? wnx : wlx;
        u32 out[4];
        #pragma unroll
        for (int p = 0; p < 4; ++p) {
            int k = ks*32 + q*8 + p*2;
            float lo = W[k*128 + n*16 + lm];
            float hi = W[(k+1)*128 + n*16 + lm];
            out[p] = (u32)f2bf(lo) | ((u32)f2bf(hi) << 16);
        }
        *(uint4*)&wtf[u*4] = make_uint4(out[0], out[1], out[2], out[3]);
        return;
    }

    __shared__ float yl[64];
    __shared__ float sq[128];
    __shared__ float yv[128];
    __shared__ float cpart[240];

    const int b  = bx >> 1;
    const int br = bx & 1;
    const float* w1 = br ? nw1 : lw1;
    const float* b1 = br ? nb1 : lb1;

    // --- y_trans for this b ---
    if (tid < 64) yl[tid] = y[b*64 + tid];
    __syncthreads();
    float v = 0.f;
    if (tid < 128) {
        float acc = bty[tid];
        for (int k = 0; k < 64; ++k) acc = fmaf(yl[k], wty[k*128 + tid], acc);
        float a = aty[0];
        v = (acc >= 0.f) ? acc : a * acc;
        sq[tid] = v * v;
    }
    __syncthreads();
    for (int s = 64; s >= 1; s >>= 1) { if (tid < s) sq[tid] += sq[tid+s]; __syncthreads(); }
    if (tid < 128) yv[tid] = v * (1.f / fmaxf(sqrtf(sq[0]), 1e-12f));
    __syncthreads();

    // --- WeffT fragments: unit = fragrow*64+lane, fragrow = h*6+nj*2+ks ---
    for (int u = tid; u < 768; u += 256) {
        int lane = u & 63, fr = u >> 6;
        int h = fr / 6, t = fr % 6, nj = t >> 1, ks = t & 1;
        int q = lane >> 4, lm = lane & 15, j = nj*16 + lm;
        u32 out[4];
        #pragma unroll
        for (int p = 0; p < 4; ++p) {
            u32 w = 0;
            #pragma unroll
            for (int e = 0; e < 2; ++e) {
                int k = ks*32 + q*8 + p*2 + e;
                float val = 0.f;
                if (j < 40)
                    val = w1[k*40 + j] + w1[(128+k)*40 + j] + yv[h*64 + k] * w1[(64+k)*40 + j];
                w |= ((u32)f2bf(val)) << (16*e);
            }
            out[p] = w;
        }
        *(uint4*)&weff[((size_t)(br*NB + b)*12 + fr)*64*4 + lane*4] =
            make_uint4(out[0], out[1], out[2], out[3]);
    }

    // --- Cs partials: 240 threads, cj = h*40+j, slice of 120 terms ---
    if (tid < 240) {
        int cj = tid / 3, sl = tid % 3;
        int h = cj / 40, j = cj % 40;
        float acc = 0.f;
        for (int t = sl*40; t < sl*40 + 40; ++t) {
            if (t < 64) {
                acc = fmaf(yv[h*64 + t], w1[(192+t)*40 + j] - w1[(128+t)*40 + j], acc);
            } else {
                int u = t - 64;
                float sv, wv;
                if (u < 32)      { sv = uid[b*32 + u];        wv = w1[(256+u)*40 + j]; }
                else if (u < 40) { sv = ose[b*8 + (u-32)];    wv = w1[(288+(u-32))*40 + j]; }
                else             { sv = zipc[b*16 + (u-40)];  wv = w1[(296+(u-40))*40 + j]; }
                acc = fmaf(sv, wv, acc);
            }
        }
        cpart[tid] = acc;
    }
    __syncthreads();
    if (tid < 96) {
        int h = tid / 48, jj = tid % 48;
        float val = 0.f;
        if (jj < 40) {
            int cj = h*40 + jj;
            val = b1[jj] + cpart[cj*3] + cpart[cj*3+1] + cpart[cj*3+2];
        }
        cs[(size_t)(br*NB + b)*96 + tid] = val;
    }
}

// ---- main v6: 512 threads (8 waves) per (b,br); 8 iters/wave; fully resident
//  (512 blocks x 64.6KB LDS = 2 blocks/CU -> 16 waves/CU = 4 waves/SIMD, no tail).
//  r3's geometry + r4/r5 register discipline: __launch_bounds__(512,2) so the RA
//  cap is 128 (observed rule: cap = 2x declared min), natural demand ~84 -> no
//  spill.  Inner loop byte-identical to r5 (1-deep prefetch, anti-LICM guard).
__global__ __launch_bounds__(512, 2) void main_kernel(
    const float* __restrict__ xloc, const float* __restrict__ xnon,
    const float* __restrict__ blx,  const float* __restrict__ alx,
    const float* __restrict__ bnx,  const float* __restrict__ anx,
    const float* __restrict__ la1,  const float* __restrict__ lw2, const float* __restrict__ lb2,
    const float* __restrict__ na1,  const float* __restrict__ nw2, const float* __restrict__ nb2,
    const u32* __restrict__ wtf, const u32* __restrict__ weff, const float* __restrict__ cs,
    float* __restrict__ out)
{
    __shared__ u16   tn[8*16*136];   // per-wave 16x128 bf16 tile, stride 136 (34816 B)
    __shared__ u32   bf_sm[4096];    // 16 frags x 64 lanes x 16B = 16 KB
    __shared__ u32   cf_sm[3072];    // 12 frags x 64 lanes x 16B = 12 KB
    __shared__ float bias_sm[128];
    __shared__ float cs_sm[96];
    __shared__ float w2_sm[48];
    // total 64576 B -> 2 blocks/CU; grid 512 = 2/CU -> fully resident, no tail

    const int tid  = threadIdx.x;
    const int b    = blockIdx.x;
    const int br   = blockIdx.y;
    const int w    = tid >> 6;       // 0..7
    const int lane = tid & 63;
    const int q    = lane >> 4;
    const int lm   = lane & 15;

    const float* xg   = br ? xnon : xloc;
    const float* bias = br ? bnx  : blx;
    const float  am1  = (br ? anx[0] : alx[0]) - 1.f;   // prelu: v + (a-1)*min(v,0)
    const float  a1m1 = (br ? na1[0] : la1[0]) - 1.f;
    const float  b2v  = br ? nb2[0] : lb2[0];
    const float* w2   = br ? nw2  : lw2;

    // ---- stage weights into LDS (coalesced 16B, 512 threads) ----
    {
        const uint4* wsrc = (const uint4*)wtf + br*1024;
        uint4* bdst = (uint4*)bf_sm;
        bdst[tid]       = wsrc[tid];
        bdst[512 + tid] = wsrc[512 + tid];
        const uint4* csrc = (const uint4*)weff + (size_t)(br*NB + b)*768;
        uint4* cdst = (uint4*)cf_sm;
        cdst[tid] = csrc[tid];
        if (tid < 256) cdst[512 + tid] = csrc[512 + tid];
    }
    if (tid < 128) bias_sm[tid] = bias[tid];
    if (tid < 96)  cs_sm[tid]   = cs[(size_t)(br*NB + b)*96 + tid];
    if (tid < 48)  w2_sm[tid]   = (tid < 40) ? w2[tid] : 0.f;

    __syncthreads();

    u16* tw = &tn[w*2176];
    const f4_t zero4 = {0.f, 0.f, 0.f, 0.f};
    float outp[8][4];
    #pragma unroll
    for (int c = 0; c < 8; ++c)
        #pragma unroll
        for (int r = 0; r < 4; ++r) outp[c][r] = 0.f;

    const float* xb = &xg[(size_t)b*NS*64];
    // wave w, iter it -> row tile it*8 + w (64 tiles total); rows tile*16 + lm

    float4 p0, p1, p2, p3;
    {
        const float* xr = xb + (size_t)(w*16 + lm)*64;   // it = 0
        p0 = *(const float4*)(xr + q*8);
        p1 = *(const float4*)(xr + q*8 + 4);
        p2 = *(const float4*)(xr + 32 + q*8);
        p3 = *(const float4*)(xr + 32 + q*8 + 4);
    }

    #pragma unroll 1
    for (int it = 0; it < 8; ++it) {
        // opaque zero: blocks LICM from hoisting loop-invariant LDS reads
        u32 zoff = 0;
        asm volatile("" : "+v"(zoff));
        const u32*   bfp = bf_sm + zoff;
        const u32*   cfp = cf_sm + zoff;
        const float* bip = bias_sm + zoff;
        const float* cvp = cs_sm + zoff;
        const float* w2p = w2_sm + zoff;

        float4 c0 = p0, c1 = p1, c2 = p2, c3 = p3;
        if (it < 7) {
            const float* xr = xb + (size_t)(((it+1)*8 + w)*16 + lm)*64;
            p0 = *(const float4*)(xr + q*8);
            p1 = *(const float4*)(xr + q*8 + 4);
            p2 = *(const float4*)(xr + 32 + q*8);
            p3 = *(const float4*)(xr + 32 + q*8 + 4);
        }

        union { u32 u[4]; bf8_t v; } A0, A1;
        A0.u[0] = pack_trunc(c0.x, c0.y); A0.u[1] = pack_trunc(c0.z, c0.w);
        A0.u[2] = pack_trunc(c1.x, c1.y); A0.u[3] = pack_trunc(c1.z, c1.w);
        A1.u[0] = pack_trunc(c2.x, c2.y); A1.u[1] = pack_trunc(c2.z, c2.w);
        A1.u[2] = pack_trunc(c3.x, c3.y); A1.u[3] = pack_trunc(c3.z, c3.w);

        // ---- Phase B': t^T = W^T @ x^T (operand swap), bias via C-init ----
        float tv[8][4];
        float s0 = 0.f, s1 = 0.f, s2 = 0.f, s3 = 0.f;
        #pragma unroll
        for (int c = 0; c < 8; ++c) {
            f4_t bi = *(const f4_t*)&bip[c*16 + q*4];
            bf8_t bf0 = *(const bf8_t*)&bfp[((c*2 + 0)*64 + lane)*4];
            bf8_t bf1 = *(const bf8_t*)&bfp[((c*2 + 1)*64 + lane)*4];
            f4_t acc = __builtin_amdgcn_mfma_f32_16x16x32_bf16(bf0, A0.v, bi,  0, 0, 0);
            acc      = __builtin_amdgcn_mfma_f32_16x16x32_bf16(bf1, A1.v, acc, 0, 0, 0);
            float v0 = acc[0]; v0 = fmaf(fminf(v0, 0.f), am1, v0); tv[c][0] = v0; s0 = fmaf(v0, v0, s0);
            float v1 = acc[1]; v1 = fmaf(fminf(v1, 0.f), am1, v1); tv[c][1] = v1; s1 = fmaf(v1, v1, s1);
            float v2 = acc[2]; v2 = fmaf(fminf(v2, 0.f), am1, v2); tv[c][2] = v2; s2 = fmaf(v2, v2, s2);
            float v3 = acc[3]; v3 = fmaf(fminf(v3, 0.f), am1, v3); tv[c][3] = v3; s3 = fmaf(v3, v3, s3);
        }
        float ssq = (s0 + s1) + (s2 + s3);      // this lane: 32 cols of row lm
        ssq += __shfl_xor(ssq, 16);
        ssq += __shfl_xor(ssq, 32);
        const float rinv = 1.f / fmaxf(sqrtf(ssq), 1e-12f);

        // unnormalized t -> wave-private LDS (rinv folded downstream)
        #pragma unroll
        for (int c = 0; c < 8; ++c) {
            u32 lo = pack_trunc(tv[c][0], tv[c][1]);
            u32 hi = pack_trunc(tv[c][2], tv[c][3]);
            *(uint2*)&tw[lm*136 + c*16 + q*4] = make_uint2(lo, hi);
        }

        // ---- Phase C': p^T = Weff^T @ t^T; in-lane j-reduction ----
        float pw[2];
        #pragma unroll
        for (int h = 0; h < 2; ++h) {
            bf8_t ac0 = *(const bf8_t*)&tw[lm*136 + h*64 + q*8];
            bf8_t ac1 = *(const bf8_t*)&tw[lm*136 + h*64 + 32 + q*8];
            float pp[3];
            #pragma unroll
            for (int nj = 0; nj < 3; ++nj) {
                f4_t cv = *(const f4_t*)&cvp[h*48 + nj*16 + q*4];
                f4_t wv = *(const f4_t*)&w2p[nj*16 + q*4];
                bf8_t cf0 = *(const bf8_t*)&cfp[((h*6 + nj*2 + 0)*64 + lane)*4];
                bf8_t cf1 = *(const bf8_t*)&cfp[((h*6 + nj*2 + 1)*64 + lane)*4];
                f4_t acc = __builtin_amdgcn_mfma_f32_16x16x32_bf16(cf0, ac0, zero4, 0, 0, 0);
                acc      = __builtin_amdgcn_mfma_f32_16x16x32_bf16(cf1, ac1, acc,   0, 0, 0);
                float ppl = 0.f;
                #pragma unroll
                for (int r = 0; r < 4; ++r) {
                    float vv = fmaf(acc[r], rinv, cv[r]);       // normalize + add C
                    vv = fmaf(fminf(vv, 0.f), a1m1, vv);        // prelu
                    ppl = fmaf(vv, wv[r], ppl);
                }
                pp[nj] = ppl;
            }
            float p = (pp[0] + pp[1]) + pp[2];   // partial over this lane's 12 j's
            p += __shfl_xor(p, 16);
            p += __shfl_xor(p, 32);
            pw[h] = (p + b2v) * rinv;            // p[h][row=lm] * rinv[lm]
        }

        // ---- Phase D (registers): outp[col] += t[lm][col] * pw ----
        #pragma unroll
        for (int c = 0; c < 8; ++c)
            #pragma unroll
            for (int r = 0; r < 4; ++r)
                outp[c][r] = fmaf(tv[c][r], pw[c >> 2], outp[c][r]);
    }

    // reduce over rows (lm lanes), once
    #pragma unroll
    for (int c = 0; c < 8; ++c)
        #pragma unroll
        for (int r = 0; r < 4; ++r) {
            float v = outp[c][r];
            v += __shfl_xor(v, 1);
            v += __shfl_xor(v, 2);
            v += __shfl_xor(v, 4);
            v += __shfl_xor(v, 8);
            outp[c][r] = v;
        }

    __syncthreads();                 // all waves done with tn -> reuse as red
    float* red = (float*)tn;         // 8*128 floats = 4 KB, aliases tn
    if (lm == 0) {
        #pragma unroll
        for (int c = 0; c < 8; ++c) {
            f4_t v = { outp[c][0], outp[c][1], outp[c][2], outp[c][3] };
            *(f4_t*)&red[w*128 + c*16 + q*4] = v;
        }
    }
    __syncthreads();
    if (tid < 128) {
        float s = 0.f;
        #pragma unroll
        for (int ww = 0; ww < 8; ++ww) s += red[ww*128 + tid];
        out[((size_t)br*NB + b)*128 + tid] = s;
    }
}

extern "C" void kernel_launch(void* const* d_in, const int* in_sizes, int n_in,
                              void* d_out, int out_size, void* d_ws, size_t ws_size,
                              hipStream_t stream)
{
    const float* xl  = (const float*)d_in[0];
    const float* xn  = (const float*)d_in[1];
    const float* y   = (const float*)d_in[2];
    const float* uid = (const float*)d_in[3];
    const float* ose = (const float*)d_in[4];
    const float* zp  = (const float*)d_in[5];
    const float* wty = (const float*)d_in[6];
    const float* bty = (const float*)d_in[7];
    const float* aty = (const float*)d_in[8];
    const float* wlx = (const float*)d_in[9];
    const float* blx = (const float*)d_in[10];
    const float* alx = (const float*)d_in[11];
    const float* wnx = (const float*)d_in[12];
    const float* bnx = (const float*)d_in[13];
    const float* anx = (const float*)d_in[14];
    const float* lw1 = (const float*)d_in[15];
    const float* lb1 = (const float*)d_in[16];
    const float* la1 = (const float*)d_in[17];
    const float* lw2 = (const float*)d_in[18];
    const float* lb2 = (const float*)d_in[19];
    const float* nw1 = (const float*)d_in[20];
    const float* nb1 = (const float*)d_in[21];
    const float* na1 = (const float*)d_in[22];
    const float* nw2 = (const float*)d_in[23];
    const float* nb2 = (const float*)d_in[24];

    // ws layout (16B-aligned segments)
    u32*   wtf  = (u32*)d_ws;                               // 2048*16B = 32 KB
    u32*   weff = (u32*)((char*)d_ws + 32768);              // 512*12*64*16B = 6 MB
    float* cs   = (float*)((char*)d_ws + 32768 + 6291456);  // 512*96*4 = 192 KB

    prep_kernel<<<dim3(520), dim3(256), 0, stream>>>(
        y, wty, bty, aty, uid, ose, zp, wlx, wnx, lw1, lb1, nw1, nb1, wtf, weff, cs);
    main_kernel<<<dim3(NB, 2), dim3(512), 0, stream>>>(
        xl, xn, blx, alx, bnx, anx,
        la1, lw2, lb2, na1, nw2, nb2,
        wtf, weff, cs, (float*)d_out);
}

// Round 8
// 235.220 us; speedup vs baseline: 1.0196x; 1.0196x over previous
//
#include <hip/hip_runtime.h>

typedef unsigned short u16;
typedef unsigned int   u32;
typedef __attribute__((ext_vector_type(8))) short bf8_t;   // 8 x bf16 (4 VGPRs)
typedef __attribute__((ext_vector_type(4))) float f4_t;    // 4 x fp32 acc

#define NB 256
#define NS 1024

__device__ __forceinline__ u16 f2bf(float f){   // RNE (used in prep only)
    u32 u = __float_as_uint(f);
    return (u16)((u + 0x7fffu + ((u >> 16) & 1u)) >> 16);
}
// 2 x fp32 -> packed bf16 (truncate), single v_perm_b32
__device__ __forceinline__ u32 pack_trunc(float lo, float hi){
    return __builtin_amdgcn_perm(__float_as_uint(hi), __float_as_uint(lo), 0x07060302u);
}

// ---- fused prep: blocks 0..511 -> per-(b,br) WeffT fragments + Cs (+y_trans);
//                  blocks 512..519 -> W (x-transform) B-fragment layout ----
__global__ __launch_bounds__(256) void prep_kernel(
    const float* __restrict__ y,    const float* __restrict__ wty,
    const float* __restrict__ bty,  const float* __restrict__ aty,
    const float* __restrict__ uid,  const float* __restrict__ ose, const float* __restrict__ zipc,
    const float* __restrict__ wlx,  const float* __restrict__ wnx,
    const float* __restrict__ lw1,  const float* __restrict__ lb1,
    const float* __restrict__ nw1,  const float* __restrict__ nb1,
    u32* __restrict__ wtf, u32* __restrict__ weff, float* __restrict__ cs)
{
    const int tid = threadIdx.x;
    const int bx  = blockIdx.x;

    if (bx >= 512) {
        // ---- wtf part: unit u = (br*16 + n*2 + ks)*64 + lane ----
        int u = (bx - 512)*256 + tid;   // 0..2047
        int lane = u & 63, fr = u >> 6;
        int br = fr >> 4, t = fr & 15, n = t >> 1, ks = t & 1;
        int q = lane >> 4, lm = lane & 15;
        const float* W = br ? wnx : wlx;
        u32 out[4];
        #pragma unroll
        for (int p = 0; p < 4; ++p) {
            int k = ks*32 + q*8 + p*2;
            float lo = W[k*128 + n*16 + lm];
            float hi = W[(k+1)*128 + n*16 + lm];
            out[p] = (u32)f2bf(lo) | ((u32)f2bf(hi) << 16);
        }
        *(uint4*)&wtf[u*4] = make_uint4(out[0], out[1], out[2], out[3]);
        return;
    }

    __shared__ float yl[64];
    __shared__ float sq[128];
    __shared__ float yv[128];
    __shared__ float cpart[240];

    const int b  = bx >> 1;
    const int br = bx & 1;
    const float* w1 = br ? nw1 : lw1;
    const float* b1 = br ? nb1 : lb1;

    // --- y_trans for this b ---
    if (tid < 64) yl[tid] = y[b*64 + tid];
    __syncthreads();
    float v = 0.f;
    if (tid < 128) {
        float acc = bty[tid];
        for (int k = 0; k < 64; ++k) acc = fmaf(yl[k], wty[k*128 + tid], acc);
        float a = aty[0];
        v = (acc >= 0.f) ? acc : a * acc;
        sq[tid] = v * v;
    }
    __syncthreads();
    for (int s = 64; s >= 1; s >>= 1) { if (tid < s) sq[tid] += sq[tid+s]; __syncthreads(); }
    if (tid < 128) yv[tid] = v * (1.f / fmaxf(sqrtf(sq[0]), 1e-12f));
    __syncthreads();

    // --- WeffT fragments: unit = fragrow*64+lane, fragrow = h*6+nj*2+ks ---
    for (int u = tid; u < 768; u += 256) {
        int lane = u & 63, fr = u >> 6;
        int h = fr / 6, t = fr % 6, nj = t >> 1, ks = t & 1;
        int q = lane >> 4, lm = lane & 15, j = nj*16 + lm;
        u32 out[4];
        #pragma unroll
        for (int p = 0; p < 4; ++p) {
            u32 w = 0;
            #pragma unroll
            for (int e = 0; e < 2; ++e) {
                int k = ks*32 + q*8 + p*2 + e;
                float val = 0.f;
                if (j < 40)
                    val = w1[k*40 + j] + w1[(128+k)*40 + j] + yv[h*64 + k] * w1[(64+k)*40 + j];
                w |= ((u32)f2bf(val)) << (16*e);
            }
            out[p] = w;
        }
        *(uint4*)&weff[((size_t)(br*NB + b)*12 + fr)*64*4 + lane*4] =
            make_uint4(out[0], out[1], out[2], out[3]);
    }

    // --- Cs partials: 240 threads, cj = h*40+j, slice of 120 terms ---
    if (tid < 240) {
        int cj = tid / 3, sl = tid % 3;
        int h = cj / 40, j = cj % 40;
        float acc = 0.f;
        for (int t = sl*40; t < sl*40 + 40; ++t) {
            if (t < 64) {
                acc = fmaf(yv[h*64 + t], w1[(192+t)*40 + j] - w1[(128+t)*40 + j], acc);
            } else {
                int u = t - 64;
                float sv, wv;
                if (u < 32)      { sv = uid[b*32 + u];        wv = w1[(256+u)*40 + j]; }
                else if (u < 40) { sv = ose[b*8 + (u-32)];    wv = w1[(288+(u-32))*40 + j]; }
                else             { sv = zipc[b*16 + (u-40)];  wv = w1[(296+(u-40))*40 + j]; }
                acc = fmaf(sv, wv, acc);
            }
        }
        cpart[tid] = acc;
    }
    __syncthreads();
    if (tid < 96) {
        int h = tid / 48, jj = tid % 48;
        float val = 0.f;
        if (jj < 40) {
            int cj = h*40 + jj;
            val = b1[jj] + cpart[cj*3] + cpart[cj*3+1] + cpart[cj*3+2];
        }
        cs[(size_t)(br*NB + b)*96 + tid] = val;
    }
}

// ---- main v7: 256 threads per (b,br); 16 iters; fully resident (512 blocks).
//  r6 lesson: the limiter is the per-CU DS pipe (28 weight-frag LDS reads/iter =
//  ~28KB/wave-iter), not latency -- extra waves regressed.  Fix: ALL weight
//  fragments persistent in REGISTERS.  RA model from r1/r3/r5: cap = 2x declared
//  min-waves -> __launch_bounds__(256,1) gives cap 256; natural demand ~225 fits.
//  VGPR ~224 -> 2 waves/SIMD = same effective occupancy r5 actually ran.
__global__ __launch_bounds__(256, 1) void main_kernel(
    const float* __restrict__ xloc, const float* __restrict__ xnon,
    const float* __restrict__ blx,  const float* __restrict__ alx,
    const float* __restrict__ bnx,  const float* __restrict__ anx,
    const float* __restrict__ la1,  const float* __restrict__ lw2, const float* __restrict__ lb2,
    const float* __restrict__ na1,  const float* __restrict__ nw2, const float* __restrict__ nb2,
    const u32* __restrict__ wtf, const u32* __restrict__ weff, const float* __restrict__ cs,
    float* __restrict__ out)
{
    __shared__ u16   tn[4*16*136];   // per-wave 16x128 bf16 tile, stride 136 (17408 B)
    __shared__ float bias_sm[128];
    __shared__ float cs_sm[96];
    __shared__ float w2_sm[48];
    // total 18496 B -> LDS is no longer the residency limit; VGPR (2 waves/SIMD) is

    const int tid  = threadIdx.x;
    const int b    = blockIdx.x;
    const int br   = blockIdx.y;
    const int w    = tid >> 6;
    const int lane = tid & 63;
    const int q    = lane >> 4;
    const int lm   = lane & 15;

    const float* xg   = br ? xnon : xloc;
    const float* bias = br ? bnx  : blx;
    const float  am1  = (br ? anx[0] : alx[0]) - 1.f;   // prelu: v + (a-1)*min(v,0)
    const float  a1m1 = (br ? na1[0] : la1[0]) - 1.f;
    const float  b2v  = br ? nb2[0] : lb2[0];
    const float* w2   = br ? nw2  : lw2;

    if (tid < 128) bias_sm[tid] = bias[tid];
    if (tid < 96)  cs_sm[tid]   = cs[(size_t)(br*NB + b)*96 + tid];
    if (tid < 48)  w2_sm[tid]   = (tid < 40) ? w2[tid] : 0.f;

    // ---- ALL weight fragments persistent in registers (coalesced 16B, L2-hot) ----
    const bf8_t* wtfv  = (const bf8_t*)wtf;
    bf8_t Bfrag[8][2];
    #pragma unroll
    for (int n = 0; n < 8; ++n)
        #pragma unroll
        for (int ks = 0; ks < 2; ++ks)
            Bfrag[n][ks] = wtfv[(br*16 + n*2 + ks)*64 + lane];
    const bf8_t* weffv = (const bf8_t*)weff + (size_t)(br*NB + b)*12*64;
    bf8_t Cfrag[2][3][2];
    #pragma unroll
    for (int h = 0; h < 2; ++h)
        #pragma unroll
        for (int nj = 0; nj < 3; ++nj)
            #pragma unroll
            for (int ks = 0; ks < 2; ++ks)
                Cfrag[h][nj][ks] = weffv[(h*6 + nj*2 + ks)*64 + lane];

    float w2v[3][4];
    #pragma unroll
    for (int nj = 0; nj < 3; ++nj)
        #pragma unroll
        for (int r = 0; r < 4; ++r) {
            int j = nj*16 + q*4 + r;
            w2v[nj][r] = (j < 40) ? w2[j] : 0.f;
        }

    __syncthreads();

    u16* tw = &tn[w*2176];
    const f4_t zero4 = {0.f, 0.f, 0.f, 0.f};
    float outp[8][4];
    #pragma unroll
    for (int c = 0; c < 8; ++c)
        #pragma unroll
        for (int r = 0; r < 4; ++r) outp[c][r] = 0.f;

    const float* xb = &xg[(size_t)b*NS*64];
    // wave w, iter it -> row tile it*4 + w (64 tiles total); rows tile*16 + lm

    float4 p0, p1, p2, p3;
    {
        const float* xr = xb + (size_t)(w*16 + lm)*64;   // it = 0
        p0 = *(const float4*)(xr + q*8);
        p1 = *(const float4*)(xr + q*8 + 4);
        p2 = *(const float4*)(xr + 32 + q*8);
        p3 = *(const float4*)(xr + 32 + q*8 + 4);
    }

    #pragma unroll 1
    for (int it = 0; it < 16; ++it) {
        // opaque zero: blocks LICM from hoisting the small LDS broadcast reads
        // (hoisting bias/cs would add ~56 regs -> overflow the 256 cap)
        u32 zoff = 0;
        asm volatile("" : "+v"(zoff));
        const float* bip = bias_sm + zoff;
        const float* cvp = cs_sm + zoff;
        const float* w2p = w2_sm + zoff;

        float4 c0 = p0, c1 = p1, c2 = p2, c3 = p3;
        if (it < 15) {
            const float* xr = xb + (size_t)(((it+1)*4 + w)*16 + lm)*64;
            p0 = *(const float4*)(xr + q*8);
            p1 = *(const float4*)(xr + q*8 + 4);
            p2 = *(const float4*)(xr + 32 + q*8);
            p3 = *(const float4*)(xr + 32 + q*8 + 4);
        }

        union { u32 u[4]; bf8_t v; } A0, A1;
        A0.u[0] = pack_trunc(c0.x, c0.y); A0.u[1] = pack_trunc(c0.z, c0.w);
        A0.u[2] = pack_trunc(c1.x, c1.y); A0.u[3] = pack_trunc(c1.z, c1.w);
        A1.u[0] = pack_trunc(c2.x, c2.y); A1.u[1] = pack_trunc(c2.z, c2.w);
        A1.u[2] = pack_trunc(c3.x, c3.y); A1.u[3] = pack_trunc(c3.z, c3.w);

        // ---- Phase B': t^T = W^T @ x^T (operand swap), bias via C-init ----
        float tv[8][4];
        float s0 = 0.f, s1 = 0.f, s2 = 0.f, s3 = 0.f;
        #pragma unroll
        for (int c = 0; c < 8; ++c) {
            f4_t bi = *(const f4_t*)&bip[c*16 + q*4];
            f4_t acc = __builtin_amdgcn_mfma_f32_16x16x32_bf16(Bfrag[c][0], A0.v, bi,  0, 0, 0);
            acc      = __builtin_amdgcn_mfma_f32_16x16x32_bf16(Bfrag[c][1], A1.v, acc, 0, 0, 0);
            float v0 = acc[0]; v0 = fmaf(fminf(v0, 0.f), am1, v0); tv[c][0] = v0; s0 = fmaf(v0, v0, s0);
            float v1 = acc[1]; v1 = fmaf(fminf(v1, 0.f), am1, v1); tv[c][1] = v1; s1 = fmaf(v1, v1, s1);
            float v2 = acc[2]; v2 = fmaf(fminf(v2, 0.f), am1, v2); tv[c][2] = v2; s2 = fmaf(v2, v2, s2);
            float v3 = acc[3]; v3 = fmaf(fminf(v3, 0.f), am1, v3); tv[c][3] = v3; s3 = fmaf(v3, v3, s3);
        }
        float ssq = (s0 + s1) + (s2 + s3);      // this lane: 32 cols of row lm
        ssq += __shfl_xor(ssq, 16);
        ssq += __shfl_xor(ssq, 32);
        const float rinv = 1.f / fmaxf(sqrtf(ssq), 1e-12f);

        // unnormalized t -> wave-private LDS (rinv folded downstream)
        #pragma unroll
        for (int c = 0; c < 8; ++c) {
            u32 lo = pack_trunc(tv[c][0], tv[c][1]);
            u32 hi = pack_trunc(tv[c][2], tv[c][3]);
            *(uint2*)&tw[lm*136 + c*16 + q*4] = make_uint2(lo, hi);
        }

        // ---- Phase C': p^T = Weff^T @ t^T; in-lane j-reduction ----
        float pw[2];
        #pragma unroll
        for (int h = 0; h < 2; ++h) {
            bf8_t ac0 = *(const bf8_t*)&tw[lm*136 + h*64 + q*8];
            bf8_t ac1 = *(const bf8_t*)&tw[lm*136 + h*64 + 32 + q*8];
            float pp[3];
            #pragma unroll
            for (int nj = 0; nj < 3; ++nj) {
                f4_t cv = *(const f4_t*)&cvp[h*48 + nj*16 + q*4];
                f4_t wv = *(const f4_t*)&w2p[nj*16 + q*4];
                f4_t acc = __builtin_amdgcn_mfma_f32_16x16x32_bf16(Cfrag[h][nj][0], ac0, zero4, 0, 0, 0);
                acc      = __builtin_amdgcn_mfma_f32_16x16x32_bf16(Cfrag[h][nj][1], ac1, acc,   0, 0, 0);
                float ppl = 0.f;
                #pragma unroll
                for (int r = 0; r < 4; ++r) {
                    float vv = fmaf(acc[r], rinv, cv[r]);       // normalize + add C
                    vv = fmaf(fminf(vv, 0.f), a1m1, vv);        // prelu
                    ppl = fmaf(vv, wv[r], ppl);
                }
                pp[nj] = ppl;
            }
            float p = (pp[0] + pp[1]) + pp[2];   // partial over this lane's 12 j's
            p += __shfl_xor(p, 16);
            p += __shfl_xor(p, 32);
            pw[h] = (p + b2v) * rinv;            // p[h][row=lm] * rinv[lm]
        }

        // ---- Phase D (registers): outp[col] += t[lm][col] * pw ----
        #pragma unroll
        for (int c = 0; c < 8; ++c)
            #pragma unroll
            for (int r = 0; r < 4; ++r)
                outp[c][r] = fmaf(tv[c][r], pw[c >> 2], outp[c][r]);
    }

    // reduce over rows (lm lanes), once
    #pragma unroll
    for (int c = 0; c < 8; ++c)
        #pragma unroll
        for (int r = 0; r < 4; ++r) {
            float v = outp[c][r];
            v += __shfl_xor(v, 1);
            v += __shfl_xor(v, 2);
            v += __shfl_xor(v, 4);
            v += __shfl_xor(v, 8);
            outp[c][r] = v;
        }

    __syncthreads();                 // all waves done with tn -> reuse as red
    float* red = (float*)tn;         // 4*128 floats = 2 KB, aliases tn
    if (lm == 0) {
        #pragma unroll
        for (int c = 0; c < 8; ++c) {
            f4_t v = { outp[c][0], outp[c][1], outp[c][2], outp[c][3] };
            *(f4_t*)&red[w*128 + c*16 + q*4] = v;
        }
    }
    __syncthreads();
    if (tid < 128) {
        float s = red[tid] + red[128 + tid] + red[256 + tid] + red[384 + tid];
        out[((size_t)br*NB + b)*128 + tid] = s;
    }
}

extern "C" void kernel_launch(void* const* d_in, const int* in_sizes, int n_in,
                              void* d_out, int out_size, void* d_ws, size_t ws_size,
                              hipStream_t stream)
{
    const float* xl  = (const float*)d_in[0];
    const float* xn  = (const float*)d_in[1];
    const float* y   = (const float*)d_in[2];
    const float* uid = (const float*)d_in[3];
    const float* ose = (const float*)d_in[4];
    const float* zp  = (const float*)d_in[5];
    const float* wty = (const float*)d_in[6];
    const float* bty = (const float*)d_in[7];
    const float* aty = (const float*)d_in[8];
    const float* wlx = (const float*)d_in[9];
    const float* blx = (const float*)d_in[10];
    const float* alx = (const float*)d_in[11];
    const float* wnx = (const float*)d_in[12];
    const float* bnx = (const float*)d_in[13];
    const float* anx = (const float*)d_in[14];
    const float* lw1 = (const float*)d_in[15];
    const float* lb1 = (const float*)d_in[16];
    const float* la1 = (const float*)d_in[17];
    const float* lw2 = (const float*)d_in[18];
    const float* lb2 = (const float*)d_in[19];
    const float* nw1 = (const float*)d_in[20];
    const float* nb1 = (const float*)d_in[21];
    const float* na1 = (const float*)d_in[22];
    const float* nw2 = (const float*)d_in[23];
    const float* nb2 = (const float*)d_in[24];

    // ws layout (16B-aligned segments)
    u32*   wtf  = (u32*)d_ws;                               // 2048*16B = 32 KB
    u32*   weff = (u32*)((char*)d_ws + 32768);              // 512*12*64*16B = 6 MB
    float* cs   = (float*)((char*)d_ws + 32768 + 6291456);  // 512*96*4 = 192 KB

    prep_kernel<<<dim3(520), dim3(256), 0, stream>>>(
        y, wty, bty, aty, uid, ose, zp, wlx, wnx, lw1, lb1, nw1, nb1, wtf, weff, cs);
    main_kernel<<<dim3(NB, 2), dim3(256), 0, stream>>>(
        xl, xn, blx, alx, bnx, anx,
        la1, lw2, lb2, na1, nw2, nb2,
        wtf, weff, cs, (float*)d_out);
}